// Round 6
// baseline (566.605 us; speedup 1.0000x reference)
//
#include <hip/hip_runtime.h>

// TopKActivation: per row of [4096, 16384] fp32, keep top-k (k=128), zero the
// rest. R5 post-mortem: 168 us with nothing saturated (VALU 25%, HBM 2.4 TB/s)
// => phase serialization: wave0-only bisection idles 15/16 waves, and all
// 256 MB of stores wait for the exact threshold. R6: (1) elements outside the
// bracket window [A,B) are decided as soon as cA/cB are known -> store ~89% of
// float4 groups BEFORE the bisection, defer only groups holding a window
// element; (2) all 16 waves bisect redundantly on a register copy of the
// (zero-padded) candidate list -> no idle-wave phase, no barrier after the
// bulk stores (they drain during the bisect). Exact fallback preserved.

constexpr int COLS  = 16384;
constexpr int NT    = 1024;            // threads per block
constexpr int PER_T = COLS / NT;       // 16 elements per thread
constexpr int NV4   = PER_T / 4;       // 4 float4 per thread
constexpr int NW    = NT / 64;         // 16 waves
constexpr int CAP   = 2048;            // LDS candidate buffer (fallback)
constexpr int CAPW  = 1024;            // fast-path window cap (16 regs/lane)

typedef float v4f __attribute__((ext_vector_type(4)));
typedef unsigned int v4u __attribute__((ext_vector_type(4)));

// Monotone float->uint key: order(key) == order(float), all finite values.
__device__ __forceinline__ unsigned int f2key(float f) {
  unsigned int b = __float_as_uint(f);
  return b ^ ((unsigned int)((int)b >> 31) | 0x80000000u);
}
__device__ __forceinline__ float key2f(unsigned int k) {
  unsigned int b = (k & 0x80000000u) ? (k ^ 0x80000000u) : ~k;
  return __uint_as_float(b);
}

__global__ void __launch_bounds__(NT, 8)
topk_scatter_kernel(const float* __restrict__ x, const int* __restrict__ kptr,
                    float* __restrict__ out) {
  const int t    = threadIdx.x;
  const int lane = t & 63;
  const int wid  = t >> 6;
  const long long row = blockIdx.x;
  const int K = *kptr;   // 128

  __shared__ int redA[NW], redB[NW];        // bracket counts
  __shared__ int red2[2][NW];               // fallback reduce, parity-buffered
  __shared__ unsigned int cand[CAP];        // compacted candidate keys
  __shared__ int cand_n;
  __shared__ unsigned int flags[COLS / 32]; // rare-path tie bitmask (2 KB)

  const float4* xrow = reinterpret_cast<const float4*>(x + row * COLS);
  v4f*          orow = reinterpret_cast<v4f*>(out + row * COLS);

  // ---- load + transform; keys stay in registers (16/thread) -------------
  unsigned int key[PER_T];
  #pragma unroll
  for (int r = 0; r < NV4; ++r) {
    float4 v = xrow[r * NT + t];
    key[4 * r + 0] = f2key(v.x);
    key[4 * r + 1] = f2key(v.y);
    key[4 * r + 2] = f2key(v.z);
    key[4 * r + 3] = f2key(v.w);
  }

  // ---- bracket pass: count >= A and >= B in one register sweep ----------
  const unsigned int A = f2key(1.9f);
  const unsigned int B = f2key(3.2f);
  int cwA = 0, cwB = 0;
  #pragma unroll
  for (int r = 0; r < PER_T; ++r) {
    cwA += __popcll(__ballot(key[r] >= A));
    cwB += __popcll(__ballot(key[r] >= B));
  }
  if (lane == 0) { redA[wid] = cwA; redB[wid] = cwB; }
  if (t == 0) cand_n = 0;
  cand[t] = 0u;                    // zero-pad fast-path window (t < 1024)
  __syncthreads();                                   // barrier 1
  int cA = 0, cB = 0;
  #pragma unroll
  for (int w = 0; w < NW; ++w) { cA += redA[w]; cB += redB[w]; }

  unsigned int T;
  int E, R;
  const bool fast = (cA >= K) && (cB < K) && ((cA - cB) <= CAPW);

  if (fast) {
    // ---- compact window candidates to LDS (once) ------------------------
    #pragma unroll
    for (int r = 0; r < PER_T; ++r) {
      const unsigned int kk = key[r];
      if (kk >= A && kk < B) {
        const int p = atomicAdd(&cand_n, 1);
        cand[p] = kk;
      }
    }
    __syncthreads();                                 // barrier 2 (lgkm only)

    // ---- bulk stores for decided groups; defer window groups ------------
    // T in [A, B-1]: key < A  => key < T or ==? no: key < A <= T -> zero;
    //                key >= B => key > T -> keep.
    unsigned int dmask = 0u;
    #pragma unroll
    for (int r = 0; r < NV4; ++r) {
      bool win = false;
      #pragma unroll
      for (int j = 0; j < 4; ++j) {
        const unsigned int kk = key[4 * r + j];
        win |= (kk >= A && kk < B);
      }
      if (win) {
        dmask |= (1u << r);
      } else {
        v4f vals;
        #pragma unroll
        for (int j = 0; j < 4; ++j) {
          const unsigned int kk = key[4 * r + j];
          vals[j] = (kk >= B) ? key2f(kk) : 0.0f;
        }
        __builtin_nontemporal_store(vals, &orow[r * NT + t]);
      }
    }

    // ---- every wave: register copy of candidates, redundant bisection ---
    const v4u* cv4 = reinterpret_cast<const v4u*>(cand);
    v4u cv[4];
    #pragma unroll
    for (int j = 0; j < 4; ++j) cv[j] = cv4[j * 64 + lane];  // 16 entries/lane

    unsigned int lo = A, hi = B - 1u;
    int cnt_lo = cA, cnt_hi1 = cB;
    while (lo < hi) {
      const unsigned int mid = lo + ((hi - lo) >> 1) + 1u;   // in [lo+1, hi]
      int c = cB;
      #pragma unroll
      for (int j = 0; j < 4; ++j) {
        #pragma unroll
        for (int e = 0; e < 4; ++e)
          c += __popcll(__ballot(cv[j][e] >= mid));  // pad 0 < mid: never counts
      }
      if (c >= K) { lo = mid; cnt_lo = c; }
      else        { hi = mid - 1u; cnt_hi1 = c; }
    }
    T = lo; E = cnt_lo - cnt_hi1; R = K - cnt_hi1;

    const bool need_rank = (E != R);   // duplicates straddling the boundary
    if (need_rank) {
      // rare: mark equal elements, keep the R lowest-indexed ones
      for (int w = t; w < COLS / 32; w += NT) flags[w] = 0u;
      __syncthreads();
      #pragma unroll
      for (int r = 0; r < NV4; ++r) {
        #pragma unroll
        for (int j = 0; j < 4; ++j) {
          if (key[4 * r + j] == T) {
            const int col = (r * NT + t) * 4 + j;
            atomicOr(&flags[col >> 5], 1u << (col & 31));
          }
        }
      }
      __syncthreads();
    }

    // ---- deferred stores (groups containing window elements) ------------
    #pragma unroll
    for (int r = 0; r < NV4; ++r) {
      if (dmask & (1u << r)) {
        v4f vals;
        #pragma unroll
        for (int j = 0; j < 4; ++j) {
          const unsigned int kk = key[4 * r + j];
          bool keep;
          if (kk > T) {
            keep = true;
          } else if (kk == T) {
            if (!need_rank) {
              keep = true;
            } else {
              const int col = (r * NT + t) * 4 + j;
              const int w_hi = col >> 5;
              int rank = 0;
              for (int w = 0; w < w_hi; ++w) rank += __popc(flags[w]);
              rank += __popc(flags[w_hi] & ((1u << (col & 31)) - 1u));
              keep = (rank < R);
            }
          } else {
            keep = false;
          }
          vals[j] = keep ? key2f(kk) : 0.0f;
        }
        __builtin_nontemporal_store(vals, &orow[r * NT + t]);
      }
    }
    return;
  }

  // ---- exact fallback: full bitwise bisection (R2/R4-proven) ------------
  {
    unsigned int lo = 0u, hi = 0xFFFFFFFFu;
    int cnt_lo = COLS, cnt_hi1 = 0;
    int base = 0, cN = 0;
    bool compacted = false;
    int par = 0;
    while (lo < hi) {
      const unsigned int mid = lo + ((hi - lo) >> 1) + 1u;
      int c;
      if (!compacted) {
        int cw = 0;
        #pragma unroll
        for (int r = 0; r < PER_T; ++r)
          cw += __popcll(__ballot(key[r] >= mid));
        if (lane == 0) red2[par][wid] = cw;
        __syncthreads();
        c = 0;
        #pragma unroll
        for (int w = 0; w < NW; ++w) c += red2[par][w];
        par ^= 1;
      } else {
        int cw = 0;
        for (int j0 = 0; j0 < cN; j0 += 64) {
          const int j = j0 + lane;
          const unsigned int v = (j < cN) ? cand[j] : 0u;
          cw += __popcll(__ballot(v >= mid));
        }
        c = base + cw;
      }
      if (c >= K) { lo = mid; cnt_lo = c; }
      else        { hi = mid - 1u; cnt_hi1 = c; }

      if (!compacted && lo < hi && (cnt_lo - cnt_hi1) <= CAP) {
        if (t == 0) cand_n = 0;
        __syncthreads();
        #pragma unroll
        for (int r = 0; r < PER_T; ++r) {
          const unsigned int kk = key[r];
          if (kk >= lo && kk <= hi) {
            const int p = atomicAdd(&cand_n, 1);
            cand[p] = kk;
          }
        }
        __syncthreads();
        cN = cnt_lo - cnt_hi1;
        base = cnt_hi1;
        compacted = true;
      }
    }
    T = lo; E = cnt_lo - cnt_hi1; R = K - cnt_hi1;
  }

  const bool need_rank = (E != R);
  if (need_rank) {
    for (int w = t; w < COLS / 32; w += NT) flags[w] = 0u;
    __syncthreads();
    #pragma unroll
    for (int r = 0; r < NV4; ++r) {
      #pragma unroll
      for (int j = 0; j < 4; ++j) {
        if (key[4 * r + j] == T) {
          const int col = (r * NT + t) * 4 + j;
          atomicOr(&flags[col >> 5], 1u << (col & 31));
        }
      }
    }
    __syncthreads();
  }

  #pragma unroll
  for (int r = 0; r < NV4; ++r) {
    v4f vals;
    #pragma unroll
    for (int j = 0; j < 4; ++j) {
      const unsigned int kk = key[4 * r + j];
      bool keep;
      if (kk > T) {
        keep = true;
      } else if (kk == T) {
        if (!need_rank) {
          keep = true;
        } else {
          const int col = (r * NT + t) * 4 + j;
          const int w_hi = col >> 5;
          int rank = 0;
          for (int w = 0; w < w_hi; ++w) rank += __popc(flags[w]);
          rank += __popc(flags[w_hi] & ((1u << (col & 31)) - 1u));
          keep = (rank < R);
        }
      } else {
        keep = false;
      }
      vals[j] = keep ? key2f(kk) : 0.0f;
    }
    __builtin_nontemporal_store(vals, &orow[r * NT + t]);
  }
}

extern "C" void kernel_launch(void* const* d_in, const int* in_sizes, int n_in,
                              void* d_out, int out_size, void* d_ws, size_t ws_size,
                              hipStream_t stream) {
  const float* x    = (const float*)d_in[0];
  const int*   kptr = (const int*)d_in[1];
  float*       out  = (float*)d_out;
  const int rows = in_sizes[0] / COLS;  // 4096
  topk_scatter_kernel<<<rows, NT, 0, stream>>>(x, kptr, out);
}

// Round 7
// 468.759 us; speedup vs baseline: 1.2087x; 1.2087x over previous
//
#include <hip/hip_runtime.h>

// TopKActivation: per row of [4096, 16384] fp32, keep top-k (k=128), zero the
// rest. R6 post-mortem: splitting the store stream (early bulk + deferred
// holes) caused 56 MB write amplification (partial-cacheline NT stores) and
// regressed to 295 us. R7: single fully-coalesced store pass (R5-proven),
// all-wave redundant register bisection (no wave0 idle phase), NT=512 with
// __launch_bounds__(512,8) for 4 co-resident blocks/CU so serial phases hide
// behind other blocks' memory phases. Bracket [2.2,2.7) from order statistics
// (window count 171+-17, cap 512 = +20 sigma); exact fallback for anything else.

constexpr int COLS  = 16384;
constexpr int NT    = 512;             // threads per block
constexpr int PER_T = COLS / NT;       // 32 elements per thread
constexpr int NV4   = PER_T / 4;       // 8 float4 per thread
constexpr int NW    = NT / 64;         // 8 waves
constexpr int CAP   = 2048;            // LDS candidate buffer (fallback)
constexpr int CAPW  = 512;             // fast-path window cap (8 regs/lane)

typedef float v4f __attribute__((ext_vector_type(4)));
typedef unsigned int v4u __attribute__((ext_vector_type(4)));

// Monotone float->uint key: order(key) == order(float), all finite values.
__device__ __forceinline__ unsigned int f2key(float f) {
  unsigned int b = __float_as_uint(f);
  return b ^ ((unsigned int)((int)b >> 31) | 0x80000000u);
}
__device__ __forceinline__ float key2f(unsigned int k) {
  unsigned int b = (k & 0x80000000u) ? (k ^ 0x80000000u) : ~k;
  return __uint_as_float(b);
}

__global__ void __launch_bounds__(NT, 8)
topk_scatter_kernel(const float* __restrict__ x, const int* __restrict__ kptr,
                    float* __restrict__ out) {
  const int t    = threadIdx.x;
  const int lane = t & 63;
  const int wid  = t >> 6;
  const long long row = blockIdx.x;
  const int K = *kptr;   // 128

  __shared__ int redA[NW], redB[NW];        // bracket counts
  __shared__ int red2[2][NW];               // fallback reduce, parity-buffered
  __shared__ unsigned int cand[CAP];        // compacted candidate keys
  __shared__ int cand_n;
  __shared__ unsigned int flags[COLS / 32]; // rare-path tie bitmask (2 KB)

  const float4* xrow = reinterpret_cast<const float4*>(x + row * COLS);
  v4f*          orow = reinterpret_cast<v4f*>(out + row * COLS);

  // ---- load + transform; keys stay in registers (32/thread) -------------
  unsigned int key[PER_T];
  #pragma unroll
  for (int r = 0; r < NV4; ++r) {
    float4 v = xrow[r * NT + t];
    key[4 * r + 0] = f2key(v.x);
    key[4 * r + 1] = f2key(v.y);
    key[4 * r + 2] = f2key(v.z);
    key[4 * r + 3] = f2key(v.w);
  }

  // ---- bracket pass: count >= A and >= B in one register sweep ----------
  const unsigned int A = f2key(2.2f);
  const unsigned int B = f2key(2.7f);
  int cwA = 0, cwB = 0;
  #pragma unroll
  for (int r = 0; r < PER_T; ++r) {
    cwA += __popcll(__ballot(key[r] >= A));
    cwB += __popcll(__ballot(key[r] >= B));
  }
  if (lane == 0) { redA[wid] = cwA; redB[wid] = cwB; }
  if (t == 0) cand_n = 0;
  cand[t] = 0u;                    // zero-pad fast-path window (t < CAPW ok: NT=512)
  __syncthreads();                                   // barrier 1
  int cA = 0, cB = 0;
  #pragma unroll
  for (int w = 0; w < NW; ++w) { cA += redA[w]; cB += redB[w]; }

  unsigned int T;
  int E, R;
  const bool fast = (cA >= K) && (cB < K) && ((cA - cB) <= CAPW);

  if (fast) {
    // ---- compact window candidates to LDS (once) ------------------------
    #pragma unroll
    for (int r = 0; r < PER_T; ++r) {
      const unsigned int kk = key[r];
      if (kk >= A && kk < B) {
        const int p = atomicAdd(&cand_n, 1);
        cand[p] = kk;
      }
    }
    __syncthreads();                                 // barrier 2

    // ---- every wave: register copy of candidates, redundant bisection ---
    const v4u* cv4 = reinterpret_cast<const v4u*>(cand);
    v4u cv[2];
    #pragma unroll
    for (int j = 0; j < 2; ++j) cv[j] = cv4[j * 64 + lane];  // 8 entries/lane

    unsigned int lo = A, hi = B - 1u;
    int cnt_lo = cA, cnt_hi1 = cB;
    while (lo < hi) {
      const unsigned int mid = lo + ((hi - lo) >> 1) + 1u;   // in [lo+1, hi]
      int c = cB;
      #pragma unroll
      for (int j = 0; j < 2; ++j) {
        #pragma unroll
        for (int e = 0; e < 4; ++e)
          c += __popcll(__ballot(cv[j][e] >= mid));  // pad 0 < mid: never counts
      }
      if (c >= K) { lo = mid; cnt_lo = c; }
      else        { hi = mid - 1u; cnt_hi1 = c; }
    }
    T = lo; E = cnt_lo - cnt_hi1; R = K - cnt_hi1;   // identical in all waves
  } else {
    // ---- exact fallback: full bitwise bisection (R2/R4-proven) ----------
    unsigned int lo = 0u, hi = 0xFFFFFFFFu;
    int cnt_lo = COLS, cnt_hi1 = 0;
    int base = 0, cN = 0;
    bool compacted = false;
    int par = 0;
    while (lo < hi) {
      const unsigned int mid = lo + ((hi - lo) >> 1) + 1u;
      int c;
      if (!compacted) {
        int cw = 0;
        #pragma unroll
        for (int r = 0; r < PER_T; ++r)
          cw += __popcll(__ballot(key[r] >= mid));
        if (lane == 0) red2[par][wid] = cw;
        __syncthreads();
        c = 0;
        #pragma unroll
        for (int w = 0; w < NW; ++w) c += red2[par][w];
        par ^= 1;
      } else {
        int cw = 0;
        for (int j0 = 0; j0 < cN; j0 += 64) {
          const int j = j0 + lane;
          const unsigned int v = (j < cN) ? cand[j] : 0u;
          cw += __popcll(__ballot(v >= mid));
        }
        c = base + cw;
      }
      if (c >= K) { lo = mid; cnt_lo = c; }
      else        { hi = mid - 1u; cnt_hi1 = c; }

      if (!compacted && lo < hi && (cnt_lo - cnt_hi1) <= CAP) {
        if (t == 0) cand_n = 0;
        __syncthreads();
        #pragma unroll
        for (int r = 0; r < PER_T; ++r) {
          const unsigned int kk = key[r];
          if (kk >= lo && kk <= hi) {
            const int p = atomicAdd(&cand_n, 1);
            cand[p] = kk;
          }
        }
        __syncthreads();
        cN = cnt_lo - cnt_hi1;
        base = cnt_hi1;
        compacted = true;
      }
    }
    T = lo; E = cnt_lo - cnt_hi1; R = K - cnt_hi1;
  }

  const bool need_rank = (E != R);     // duplicates straddling the boundary
  if (need_rank) {
    // rare path: mark all equal elements, keep the R lowest-indexed ones
    for (int w = t; w < COLS / 32; w += NT) flags[w] = 0u;
    __syncthreads();
    #pragma unroll
    for (int r = 0; r < NV4; ++r) {
      #pragma unroll
      for (int j = 0; j < 4; ++j) {
        if (key[4 * r + j] == T) {
          const int col = (r * NT + t) * 4 + j;
          atomicOr(&flags[col >> 5], 1u << (col & 31));
        }
      }
    }
    __syncthreads();
  }

  // ---- single coalesced write pass: val if kept, else 0 -----------------
  #pragma unroll
  for (int r = 0; r < NV4; ++r) {
    v4f vals;
    #pragma unroll
    for (int j = 0; j < 4; ++j) {
      const unsigned int kk = key[4 * r + j];
      bool keep;
      if (kk > T) {
        keep = true;
      } else if (kk == T) {
        if (!need_rank) {
          keep = true;
        } else {
          const int col = (r * NT + t) * 4 + j;
          const int w_hi = col >> 5;
          int rank = 0;
          for (int w = 0; w < w_hi; ++w) rank += __popc(flags[w]);
          rank += __popc(flags[w_hi] & ((1u << (col & 31)) - 1u));
          keep = (rank < R);
        }
      } else {
        keep = false;
      }
      vals[j] = keep ? key2f(kk) : 0.0f;
    }
    __builtin_nontemporal_store(vals, &orow[r * NT + t]);
  }
}

extern "C" void kernel_launch(void* const* d_in, const int* in_sizes, int n_in,
                              void* d_out, int out_size, void* d_ws, size_t ws_size,
                              hipStream_t stream) {
  const float* x    = (const float*)d_in[0];
  const int*   kptr = (const int*)d_in[1];
  float*       out  = (float*)d_out;
  const int rows = in_sizes[0] / COLS;  // 4096
  topk_scatter_kernel<<<rows, NT, 0, stream>>>(x, kptr, out);
}

// Round 8
// 465.658 us; speedup vs baseline: 1.2168x; 1.0067x over previous
//
#include <hip/hip_runtime.h>

// TopKActivation: per row of [4096, 16384] fp32, keep top-k (k=128), zero rest.
// R8: TWO-KERNEL SPLIT. Single-kernel variants plateau at ~168-190 us because
// each block holds its row across barrier-separated threshold phases before
// any store can issue (2 blocks/CU co-resident => no overlap), and R7's
// occupancy push just spilled (WRITE +33 MB at VGPR=32 with 32 keys/thread).
// Kernel A (1 block/row, NT=1024, PER_T=16 proven no-spill): finds exact
// threshold key T and tie cutoff column, writes 8 B/row to d_ws. Kernel B:
// pure elementwise streaming apply (no LDS, no barriers, 1 float4/thread),
// runs at copy speed; A's read leaves input L3-resident for B.

constexpr int COLS  = 16384;
constexpr int NT    = 1024;            // kernel A threads per block
constexpr int PER_T = COLS / NT;       // 16 elements per thread
constexpr int NV4   = PER_T / 4;       // 4 float4 per thread
constexpr int NW    = NT / 64;         // 16 waves
constexpr int CAP   = 2048;            // LDS candidate buffer (fallback)
constexpr int CAPW  = 512;             // fast-path window cap (8 regs/lane)
constexpr int BNT   = 256;             // kernel B threads per block

typedef float v4f __attribute__((ext_vector_type(4)));
typedef unsigned int v4u __attribute__((ext_vector_type(4)));

// Monotone float->uint key: order(key) == order(float), all finite values.
__device__ __forceinline__ unsigned int f2key(float f) {
  unsigned int b = __float_as_uint(f);
  return b ^ ((unsigned int)((int)b >> 31) | 0x80000000u);
}

// ---------------- Kernel A: per-row threshold + tie cutoff ----------------
__global__ void __launch_bounds__(NT)
topk_thresh_kernel(const float* __restrict__ x, const int* __restrict__ kptr,
                   uint2* __restrict__ tbl) {
  const int t    = threadIdx.x;
  const int lane = t & 63;
  const int wid  = t >> 6;
  const long long row = blockIdx.x;
  const int K = *kptr;   // 128

  __shared__ int redA[NW], redB[NW];
  __shared__ int red2[2][NW];
  __shared__ __align__(16) unsigned int cand[CAP];
  __shared__ int cand_n;
  __shared__ int sCut;
  __shared__ unsigned int flags[COLS / 32];

  const float4* xrow = reinterpret_cast<const float4*>(x + row * COLS);

  unsigned int key[PER_T];
  #pragma unroll
  for (int r = 0; r < NV4; ++r) {
    float4 v = xrow[r * NT + t];
    key[4 * r + 0] = f2key(v.x);
    key[4 * r + 1] = f2key(v.y);
    key[4 * r + 2] = f2key(v.z);
    key[4 * r + 3] = f2key(v.w);
  }

  // bracket pass: count >= A and >= B in one register sweep
  const unsigned int A = f2key(2.2f);
  const unsigned int B = f2key(2.7f);
  int cwA = 0, cwB = 0;
  #pragma unroll
  for (int r = 0; r < PER_T; ++r) {
    cwA += __popcll(__ballot(key[r] >= A));
    cwB += __popcll(__ballot(key[r] >= B));
  }
  if (lane == 0) { redA[wid] = cwA; redB[wid] = cwB; }
  if (t == 0) cand_n = 0;
  if (t < CAPW) cand[t] = 0u;          // zero-pad fast-path window
  __syncthreads();                                   // barrier 1
  int cA = 0, cB = 0;
  #pragma unroll
  for (int w = 0; w < NW; ++w) { cA += redA[w]; cB += redB[w]; }

  unsigned int T;
  int E, R;
  const bool fast = (cA >= K) && (cB < K) && ((cA - cB) <= CAPW);

  if (fast) {
    #pragma unroll
    for (int r = 0; r < PER_T; ++r) {
      const unsigned int kk = key[r];
      if (kk >= A && kk < B) {
        const int p = atomicAdd(&cand_n, 1);
        cand[p] = kk;
      }
    }
    __syncthreads();                                 // barrier 2

    // every wave: register copy of candidates, redundant bisection
    const v4u* cv4 = reinterpret_cast<const v4u*>(cand);
    v4u cv[2];
    #pragma unroll
    for (int j = 0; j < 2; ++j) cv[j] = cv4[j * 64 + lane];  // 8 entries/lane

    unsigned int lo = A, hi = B - 1u;
    int cnt_lo = cA, cnt_hi1 = cB;
    while (lo < hi) {
      const unsigned int mid = lo + ((hi - lo) >> 1) + 1u;
      int c = cB;
      #pragma unroll
      for (int j = 0; j < 2; ++j) {
        #pragma unroll
        for (int e = 0; e < 4; ++e)
          c += __popcll(__ballot(cv[j][e] >= mid));
      }
      if (c >= K) { lo = mid; cnt_lo = c; }
      else        { hi = mid - 1u; cnt_hi1 = c; }
    }
    T = lo; E = cnt_lo - cnt_hi1; R = K - cnt_hi1;   // identical in all waves
  } else {
    // exact fallback: full bitwise bisection (R2/R4-proven)
    unsigned int lo = 0u, hi = 0xFFFFFFFFu;
    int cnt_lo = COLS, cnt_hi1 = 0;
    int base = 0, cN = 0;
    bool compacted = false;
    int par = 0;
    while (lo < hi) {
      const unsigned int mid = lo + ((hi - lo) >> 1) + 1u;
      int c;
      if (!compacted) {
        int cw = 0;
        #pragma unroll
        for (int r = 0; r < PER_T; ++r)
          cw += __popcll(__ballot(key[r] >= mid));
        if (lane == 0) red2[par][wid] = cw;
        __syncthreads();
        c = 0;
        #pragma unroll
        for (int w = 0; w < NW; ++w) c += red2[par][w];
        par ^= 1;
      } else {
        int cw = 0;
        for (int j0 = 0; j0 < cN; j0 += 64) {
          const int j = j0 + lane;
          const unsigned int v = (j < cN) ? cand[j] : 0u;
          cw += __popcll(__ballot(v >= mid));
        }
        c = base + cw;
      }
      if (c >= K) { lo = mid; cnt_lo = c; }
      else        { hi = mid - 1u; cnt_hi1 = c; }

      if (!compacted && lo < hi && (cnt_lo - cnt_hi1) <= CAP) {
        if (t == 0) cand_n = 0;
        __syncthreads();
        #pragma unroll
        for (int r = 0; r < PER_T; ++r) {
          const unsigned int kk = key[r];
          if (kk >= lo && kk <= hi) {
            const int p = atomicAdd(&cand_n, 1);
            cand[p] = kk;
          }
        }
        __syncthreads();
        cN = cnt_lo - cnt_hi1;
        base = cnt_hi1;
        compacted = true;
      }
    }
    T = lo; E = cnt_lo - cnt_hi1; R = K - cnt_hi1;
  }

  // tie cutoff: keep equals with col < cutoff. E==R (common): keep all -> COLS.
  int cutoff = COLS;
  if (E != R) {
    for (int w = t; w < COLS / 32; w += NT) flags[w] = 0u;
    __syncthreads();
    #pragma unroll
    for (int r = 0; r < NV4; ++r) {
      #pragma unroll
      for (int j = 0; j < 4; ++j) {
        if (key[4 * r + j] == T) {
          const int col = (r * NT + t) * 4 + j;
          atomicOr(&flags[col >> 5], 1u << (col & 31));
        }
      }
    }
    __syncthreads();
    // the thread owning the (R-1)-ranked equal publishes cutoff = col+1
    #pragma unroll
    for (int r = 0; r < NV4; ++r) {
      #pragma unroll
      for (int j = 0; j < 4; ++j) {
        if (key[4 * r + j] == T) {
          const int col = (r * NT + t) * 4 + j;
          const int w_hi = col >> 5;
          int rank = 0;
          for (int w = 0; w < w_hi; ++w) rank += __popc(flags[w]);
          rank += __popc(flags[w_hi] & ((1u << (col & 31)) - 1u));
          if (rank == R - 1) sCut = col + 1;   // unique writer
        }
      }
    }
    __syncthreads();
    cutoff = sCut;
  }

  if (t == 0) tbl[row] = make_uint2(T, (unsigned int)cutoff);
}

// ---------------- Kernel B: pure streaming apply --------------------------
__global__ void __launch_bounds__(BNT)
topk_apply_kernel(const float* __restrict__ x, const uint2* __restrict__ tbl,
                  float* __restrict__ out) {
  const int gid = blockIdx.x * BNT + threadIdx.x;   // float4 index
  const int row = gid >> 12;                        // 4096 float4 per row
  const int c4  = gid & 4095;

  const uint2 tc = tbl[row];
  const unsigned int T = tc.x;
  const int cutoff = (int)tc.y;

  const float4 v = reinterpret_cast<const float4*>(x)[gid];
  const float vf[4] = {v.x, v.y, v.z, v.w};
  v4f o;
  #pragma unroll
  for (int j = 0; j < 4; ++j) {
    const unsigned int kk = f2key(vf[j]);
    const int col = c4 * 4 + j;
    const bool keep = (kk > T) || (kk == T && col < cutoff);
    o[j] = keep ? vf[j] : 0.0f;
  }
  __builtin_nontemporal_store(o, &reinterpret_cast<v4f*>(out)[gid]);
}

extern "C" void kernel_launch(void* const* d_in, const int* in_sizes, int n_in,
                              void* d_out, int out_size, void* d_ws, size_t ws_size,
                              hipStream_t stream) {
  const float* x    = (const float*)d_in[0];
  const int*   kptr = (const int*)d_in[1];
  float*       out  = (float*)d_out;
  uint2*       tbl  = (uint2*)d_ws;                 // 4096 * 8 B = 32 KB
  const int rows = in_sizes[0] / COLS;              // 4096

  topk_thresh_kernel<<<rows, NT, 0, stream>>>(x, kptr, tbl);
  const int nblk = (rows * (COLS / 4)) / BNT;       // 65536
  topk_apply_kernel<<<nblk, BNT, 0, stream>>>(x, tbl, out);
}